// Round 4
// baseline (2640.091 us; speedup 1.0000x reference)
//
#include <hip/hip_runtime.h>
#include <hip/hip_bf16.h>
#include <math.h>

#define V_  32000
#define C_  1024
#define L_  2
#define H_  16
#define N_  64
#define B_  2
#define T_  1024
#define FF_ 4096
#define DW_ 64
#define DA_ 64
#define DV_ 32
#define DG_ 128
#define BT_  (B_*T_)
#define BTC_ (BT_*C_)

typedef float floatx4 __attribute__((ext_vector_type(4)));
typedef short shortx8 __attribute__((ext_vector_type(8)));
typedef __attribute__((address_space(1))) unsigned int gu32;
typedef __attribute__((address_space(3))) unsigned int su32;

__device__ __forceinline__ float sigf(float x){ return 1.0f/(1.0f+expf(-x)); }
__device__ __forceinline__ unsigned short f2bf(float x){
  __hip_bfloat16 h = __float2bfloat16(x);
  return *(unsigned short*)&h;
}
__device__ __forceinline__ void gload16(const void* g, void* l){
  __builtin_amdgcn_global_load_lds((const gu32*)g, (su32*)l, 16, 0, 0);
}

// 16-lane sum reduction entirely on the VALU via DPP (no DS-pipe shuffles).
__device__ __forceinline__ float dpp_red16(float s){
  s += __int_as_float(__builtin_amdgcn_update_dpp(0, __float_as_int(s), 0xB1, 0xf, 0xf, true));
  s += __int_as_float(__builtin_amdgcn_update_dpp(0, __float_as_int(s), 0x4E, 0xf, 0xf, true));
  s += __int_as_float(__builtin_amdgcn_update_dpp(0, __float_as_int(s), 0x141, 0xf, 0xf, true));
  s += __int_as_float(__builtin_amdgcn_update_dpp(0, __float_as_int(s), 0x140, 0xf, 0xf, true));
  return s;
}

// ---------------- embedding ----------------
__global__ void k_embed(const int* __restrict__ idx, const float* __restrict__ emb,
                        float* __restrict__ x){
  int i = blockIdx.x*256 + threadIdx.x;
  if (i >= BTC_) return;
  int row = i / C_, c = i - row*C_;
  x[i] = emb[(size_t)idx[row]*C_ + c];
}

// ---------------- layernorm (row-wise over C); optional bf16 output ----------------
__global__ void k_ln(const float* __restrict__ x, const float* __restrict__ g,
                     const float* __restrict__ b, float* __restrict__ out,
                     unsigned short* __restrict__ out16){
  int row = blockIdx.x;
  const float* xr = x + (size_t)row*C_;
  float s = 0.f, s2 = 0.f;
  for (int c = threadIdx.x; c < C_; c += 256){ float v = xr[c]; s += v; s2 += v*v; }
  for (int o = 32; o > 0; o >>= 1){ s += __shfl_xor(s,o); s2 += __shfl_xor(s2,o); }
  __shared__ float w1s[4], w2s[4];
  int wid = threadIdx.x >> 6, lane = threadIdx.x & 63;
  if (lane == 0){ w1s[wid] = s; w2s[wid] = s2; }
  __syncthreads();
  if (threadIdx.x == 0){
    float a = 0.f, bb = 0.f;
    for (int i = 0; i < 4; i++){ a += w1s[i]; bb += w2s[i]; }
    w1s[0] = a; w2s[0] = bb;
  }
  __syncthreads();
  float mean = w1s[0] * (1.0f/C_);
  float var  = w2s[0] * (1.0f/C_) - mean*mean;
  float r = rsqrtf(var + 1e-5f);
  if (out16){
    unsigned short* orow = out16 + (size_t)row*C_;
    for (int c = threadIdx.x; c < C_; c += 256)
      orow[c] = f2bf((xr[c]-mean)*r*g[c] + b[c]);
  } else {
    float* orow = out + (size_t)row*C_;
    for (int c = threadIdx.x; c < C_; c += 256)
      orow[c] = (xr[c]-mean)*r*g[c] + b[c];
  }
}

// ---------------- fused LN(row)+LN(prev row)+mix6 -> 6 bf16 matrices ----------------
__global__ void k_lnmix(const float* __restrict__ x, const float* __restrict__ g,
                        const float* __restrict__ b, const float* __restrict__ mixl,
                        unsigned short* __restrict__ m6){
  int row = blockIdx.x;
  int t = row & (T_-1);
  const float* xr = x + (size_t)row*C_;
  const float* xp = xr - C_;
  float s0=0.f,q0=0.f,s1=0.f,q1=0.f;
  for (int c = threadIdx.x; c < C_; c += 256){
    float v = xr[c]; s0 += v; q0 += v*v;
    if (t > 0){ float u = xp[c]; s1 += u; q1 += u*u; }
  }
  for (int o=32;o>0;o>>=1){
    s0+=__shfl_xor(s0,o); q0+=__shfl_xor(q0,o);
    s1+=__shfl_xor(s1,o); q1+=__shfl_xor(q1,o);
  }
  __shared__ float rA[4], rB[4], rC[4], rD[4];
  int wid = threadIdx.x>>6, lane = threadIdx.x&63;
  if (lane==0){ rA[wid]=s0; rB[wid]=q0; rC[wid]=s1; rD[wid]=q1; }
  __syncthreads();
  if (threadIdx.x==0){
    float a=0,bb=0,cc=0,dd=0;
    for(int i=0;i<4;i++){a+=rA[i];bb+=rB[i];cc+=rC[i];dd+=rD[i];}
    rA[0]=a;rB[0]=bb;rC[0]=cc;rD[0]=dd;
  }
  __syncthreads();
  float m0 = rA[0]*(1.f/C_);
  float r0 = rsqrtf(rB[0]*(1.f/C_)-m0*m0 + 1e-5f);
  float m1=0.f, r1=0.f;
  if (t>0){ m1 = rC[0]*(1.f/C_); r1 = rsqrtf(rD[0]*(1.f/C_)-m1*m1 + 1e-5f); }
  size_t base = (size_t)row*C_;
  for (int c = threadIdx.x; c < C_; c += 256){
    float cur = (xr[c]-m0)*r0*g[c]+b[c];
    float pv  = (t>0) ? (xp[c]-m1)*r1*g[c]+b[c] : 0.f;
    float d = pv - cur;
#pragma unroll
    for (int j=0;j<6;j++)
      m6[(size_t)j*BTC_ + base + c] = f2bf(cur + d*mixl[j*C_+c]);
  }
}

// ---------------- fused LN + FFN token-mix -> bf16 ----------------
__global__ void k_lnffn(const float* __restrict__ x, const float* __restrict__ g,
                        const float* __restrict__ b, const float* __restrict__ fxk,
                        unsigned short* __restrict__ kx){
  int row = blockIdx.x;
  int t = row & (T_-1);
  const float* xr = x + (size_t)row*C_;
  const float* xp = xr - C_;
  float s0=0.f,q0=0.f,s1=0.f,q1=0.f;
  for (int c = threadIdx.x; c < C_; c += 256){
    float v = xr[c]; s0 += v; q0 += v*v;
    if (t > 0){ float u = xp[c]; s1 += u; q1 += u*u; }
  }
  for (int o=32;o>0;o>>=1){
    s0+=__shfl_xor(s0,o); q0+=__shfl_xor(q0,o);
    s1+=__shfl_xor(s1,o); q1+=__shfl_xor(q1,o);
  }
  __shared__ float rA[4], rB[4], rC[4], rD[4];
  int wid = threadIdx.x>>6, lane = threadIdx.x&63;
  if (lane==0){ rA[wid]=s0; rB[wid]=q0; rC[wid]=s1; rD[wid]=q1; }
  __syncthreads();
  if (threadIdx.x==0){
    float a=0,bb=0,cc=0,dd=0;
    for(int i=0;i<4;i++){a+=rA[i];bb+=rB[i];cc+=rC[i];dd+=rD[i];}
    rA[0]=a;rB[0]=bb;rC[0]=cc;rD[0]=dd;
  }
  __syncthreads();
  float m0 = rA[0]*(1.f/C_);
  float r0 = rsqrtf(rB[0]*(1.f/C_)-m0*m0 + 1e-5f);
  float m1=0.f, r1=0.f;
  if (t>0){ m1 = rC[0]*(1.f/C_); r1 = rsqrtf(rD[0]*(1.f/C_)-m1*m1 + 1e-5f); }
  size_t base = (size_t)row*C_;
  for (int c = threadIdx.x; c < C_; c += 256){
    float cur = (xr[c]-m0)*r0*g[c]+b[c];
    float pv  = (t>0) ? (xp[c]-m1)*r1*g[c]+b[c] : 0.f;
    kx[base + c] = f2bf(cur + (pv - cur)*fxk[c]);
  }
}

// ---------------- kk normalize + k2 (in-place on k) + bba = -(kk*a) ----------------
__global__ void k_kk(const float* __restrict__ kkw, const float* __restrict__ kaw,
                     const float* __restrict__ a, float* __restrict__ k,
                     float* __restrict__ kk, float* __restrict__ bba){
  int bth = blockIdx.x;
  int lane = threadIdx.x;
  int bt = bth / H_, h = bth - bt*H_;
  int cix = h*N_ + lane;
  size_t gi = (size_t)bt*C_ + cix;
  float kv = k[gi];
  float kkv = kv * kkw[cix];
  float ss = kkv*kkv;
  for (int o = 32; o > 0; o >>= 1) ss += __shfl_xor(ss,o);
  float nrm = fmaxf(sqrtf(ss), 1e-12f);
  float kkn = kkv / nrm;
  kk[gi] = kkn;
  float av = a[gi];
  bba[gi] = -kkn*av;
  k[gi] = kv * (1.f + (av - 1.f)*kaw[cix]);
}

// ---------------- RWKV7 scan: rows split 8-way across blocks ----------
// Grid: 32 (b,h) x 8 row-blocks = 256 blocks. 128 threads: thread = 1 row x 4 cols.
// SCHUNK=16 double-buffered LDS staging via global_load_lds; raw s_barrier +
// counted vmcnt(16) (never drain store-acks); register-pipelined LDS reads;
// 16-lane DPP reductions.
#define SCHUNK 16
#define SROWS  8
__global__ __launch_bounds__(128) void k_scan(
    const float* __restrict__ r, const float* __restrict__ k2,
    const float* __restrict__ v, const float* __restrict__ wd,
    const float* __restrict__ kk, const float* __restrict__ bba,
    const float* __restrict__ S0, float* __restrict__ y){
  int bh = blockIdx.x & 31;
  int rblk = blockIdx.x >> 5;
  int b = bh / H_, h = bh - b*H_;
  int tid = threadIdx.x;
  int wave = tid >> 6, lane = tid & 63;
  int rg = tid >> 4;
  int row = rblk*SROWS + rg;
  int cg = tid & 15;
  int c0 = cg*4;

  // buf[bi][vec][tt][64]; vec: 0=r 1=k2 2=v 3=wd 4=kk 5=bba
  __shared__ __attribute__((aligned(16))) float buf[2][6][SCHUNK][64];

  float S[4];
  {
    const floatx4 s0 = *(const floatx4*)&S0[((size_t)h*N_ + row)*N_ + c0];
#pragma unroll
    for (int ci = 0; ci < 4; ci++) S[ci] = s0[ci];
  }

  size_t hoff = ((size_t)b*T_)*C_ + (size_t)h*N_;

  // staging: 24 wave-units of 1024B (6 vecs x 4 quarter-chunks); 12 per wave.
  auto do_stage = [&](int t0, int bi){
#pragma unroll
    for (int q = 0; q < 12; q++){
      int u = wave*12 + q;
      int vec = u >> 2, tt4 = (u & 3)*4;
      int tt = tt4 + (lane >> 4);
      const float* src;
      switch (vec){
        case 0: src = r;   break;
        case 1: src = k2;  break;
        case 2: src = v;   break;
        case 3: src = wd;  break;
        case 4: src = kk;  break;
        default: src = bba; break;
      }
      src += hoff + (size_t)(t0 + tt)*C_ + (size_t)((lane & 15)*4);
      gload16(src, &buf[bi][vec][tt4][0]);
    }
  };

  do_stage(0, 0);
  asm volatile("s_waitcnt vmcnt(0)" ::: "memory");
  __builtin_amdgcn_s_barrier();

  const int NC = T_/SCHUNK;
  size_t off = hoff;
  for (int c = 0; c < NC; c++){
    int bi = c & 1;
    bool more = (c + 1 < NC);
    if (more) do_stage((c+1)*SCHUNK, bi ^ 1);
    asm volatile("" ::: "memory");   // pin: all stage loads issue before loop stores

    // register-pipelined steps
    floatx4 rv  = *(const floatx4*)&buf[bi][0][0][c0];
    floatx4 kv  = *(const floatx4*)&buf[bi][1][0][c0];
    float   vi  = buf[bi][2][0][row];
    floatx4 dd  = *(const floatx4*)&buf[bi][3][0][c0];
    floatx4 kkv = *(const floatx4*)&buf[bi][4][0][c0];
    floatx4 bav = *(const floatx4*)&buf[bi][5][0][c0];
#pragma unroll
    for (int tt = 0; tt < SCHUNK; tt++, off += C_){
      floatx4 rv2, kv2, dd2, kkv2, bav2; float vi2;
      if (tt + 1 < SCHUNK){
        rv2  = *(const floatx4*)&buf[bi][0][tt+1][c0];
        kv2  = *(const floatx4*)&buf[bi][1][tt+1][c0];
        vi2  = buf[bi][2][tt+1][row];
        dd2  = *(const floatx4*)&buf[bi][3][tt+1][c0];
        kkv2 = *(const floatx4*)&buf[bi][4][tt+1][c0];
        bav2 = *(const floatx4*)&buf[bi][5][tt+1][c0];
      }
      // sa_pos = sum_j S[j]*kk[j]  (sign folded into bba)
      float s = S[0]*kkv[0];
      s = fmaf(S[1], kkv[1], s);
      s = fmaf(S[2], kkv[2], s);
      s = fmaf(S[3], kkv[3], s);
      float sa = dpp_red16(s);
      float yy = 0.f;
#pragma unroll
      for (int ci = 0; ci < 4; ci++){
        float t0v = fmaf(vi, kv[ci], sa*bav[ci]);
        float sn = fmaf(S[ci], dd[ci], t0v);
        S[ci] = sn;
        yy = fmaf(sn, rv[ci], yy);
      }
      float yv = dpp_red16(yy);
      if (cg == 0) y[off + row] = yv;
      if (tt + 1 < SCHUNK){
        rv = rv2; kv = kv2; vi = vi2; dd = dd2; kkv = kkv2; bav = bav2;
      }
    }
    if (more){
      // newest 16 vm-ops per wave = this chunk's y-stores; anything older
      // (the 12 prefetch loads for chunk c+1) must therefore be complete.
      asm volatile("s_waitcnt vmcnt(16)" ::: "memory");
      __builtin_amdgcn_sched_barrier(0);
      __builtin_amdgcn_s_barrier();
    }
  }
}

// ---------------- groupnorm + bonus + *g -> bf16 ----------------
__global__ void k_gnb(const float* __restrict__ lxg, const float* __restrict__ lxb,
                      const float* __restrict__ rk, const float* __restrict__ r,
                      const float* __restrict__ k2, const float* __restrict__ v,
                      const float* __restrict__ g, const float* __restrict__ y,
                      unsigned short* __restrict__ yg){
  int bth = blockIdx.x;
  int lane = threadIdx.x;
  int bt = bth / H_, h = bth - bt*H_;
  int cix = h*N_ + lane;
  size_t gi = (size_t)bt*C_ + cix;
  float yv = y[gi];
  float s = yv;
  for (int o = 32; o > 0; o >>= 1) s += __shfl_xor(s,o);
  float mean = s * (1.0f/N_);
  float d = yv - mean;
  float s2 = d*d;
  for (int o = 32; o > 0; o >>= 1) s2 += __shfl_xor(s2,o);
  float var = s2 * (1.0f/N_);
  float yn = d * rsqrtf(var + 64e-5f) * lxg[cix] + lxb[cix];
  float dv = r[gi]*k2[gi]*rk[h*N_ + lane];
  for (int o = 32; o > 0; o >>= 1) dv += __shfl_xor(dv,o);
  yg[gi] = f2bf((yn + dv*v[gi]) * g[gi]);
}

// ---------------- weight transpose + fp32->bf16: in [R][Cc] -> out [Cpad][R] ----------------
__global__ void k_tc(const float* __restrict__ in, unsigned short* __restrict__ out,
                     int R, int Cc, int Cpad){
  __shared__ float t[32][33];
  int c0 = blockIdx.x*32, r0 = blockIdx.y*32;
  int tx = threadIdx.x, ty = threadIdx.y;
  for (int i = ty; i < 32; i += 8){
    int r = r0+i, c = c0+tx;
    t[i][tx] = (r < R && c < Cc) ? in[(size_t)r*Cc + c] : 0.f;
  }
  __syncthreads();
  for (int i = ty; i < 32; i += 8){
    int oc = c0+i, orr = r0+tx;
    if (oc < Cpad && orr < R) out[(size_t)oc*R + orr] = f2bf(t[tx][i]);
  }
}

// ---------------- bf16 MFMA GEMM: C = ep(A[M][K](lda) @ Bt[N][K]^T) ----------------
// ep: 0=store f32, 1=add f32, 2=bf16, 3=tanh->bf16, 4=sigmoid->bf16, 5=relu^2->bf16,
//     6=sig(ec[col]+v)*exp(-.5) f32, 7=sig(ec[col]+v) f32, 8=vmix RMW f32
__global__ __launch_bounds__(256) void k_mgemm(
    const short* __restrict__ A, int lda, const short* __restrict__ Bt,
    float* __restrict__ Cf, unsigned short* __restrict__ Cb, int ldc,
    int K, int ep, const float* __restrict__ ec, const float* __restrict__ e1){
  __shared__ __attribute__((aligned(16))) short As[128*32];
  __shared__ __attribute__((aligned(16))) short Bs[128*32];
  int m0 = blockIdx.y*128, n0 = blockIdx.x*128;
  int tid = threadIdx.x, wave = tid >> 6, lane = tid & 63;
  int lhi = lane >> 4, llo = lane & 15;
  int wm = wave & 1, wn = wave >> 1;
  int arow = lane >> 2, acol = (lane & 3)*8;
  floatx4 acc[4][4];
#pragma unroll
  for (int i = 0; i < 4; i++)
#pragma unroll
    for (int j = 0; j < 4; j++) acc[i][j] = (floatx4){0.f,0.f,0.f,0.f};

  for (int k0 = 0; k0 < K; k0 += 32){
#pragma unroll
    for (int q = 0; q < 2; q++){
      int r0 = wave*32 + q*16;
      gload16(A  + (size_t)(m0 + r0 + arow)*lda + k0 + acol, As + r0*32);
      gload16(Bt + (size_t)(n0 + r0 + arow)*K   + k0 + acol, Bs + r0*32);
    }
    __syncthreads();
    shortx8 af[4], bfv[4];
#pragma unroll
    for (int mi = 0; mi < 4; mi++)
      af[mi] = *(const shortx8*)(As + ((wm*64 + mi*16 + llo)*32 + lhi*8));
#pragma unroll
    for (int nj = 0; nj < 4; nj++)
      bfv[nj] = *(const shortx8*)(Bs + ((wn*64 + nj*16 + llo)*32 + lhi*8));
#pragma unroll
    for (int mi = 0; mi < 4; mi++)
#pragma unroll
      for (int nj = 0; nj < 4; nj++)
        acc[mi][nj] = __builtin_amdgcn_mfma_f32_16x16x32_bf16(af[mi], bfv[nj], acc[mi][nj], 0, 0, 0);
    __syncthreads();
  }
#pragma unroll
  for (int mi = 0; mi < 4; mi++){
#pragma unroll
    for (int nj = 0; nj < 4; nj++){
      int gr0 = m0 + wm*64 + mi*16 + lhi*4;
      int gc  = n0 + wn*64 + nj*16 + llo;
#pragma unroll
      for (int rg = 0; rg < 4; rg++){
        size_t ci = (size_t)(gr0 + rg)*ldc + gc;
        float v = acc[mi][nj][rg];
        switch (ep){
          case 0: Cf[ci] = v; break;
          case 1: Cf[ci] += v; break;
          case 2: Cb[ci] = f2bf(v); break;
          case 3: Cb[ci] = f2bf(tanhf(v)); break;
          case 4: Cb[ci] = f2bf(sigf(v)); break;
          case 5: { float rr = fmaxf(v, 0.f); Cb[ci] = f2bf(rr*rr); } break;
          case 6: Cf[ci] = sigf(ec[gc] + v) * 0.60653065971263342f; break;
          case 7: Cf[ci] = sigf(ec[gc] + v); break;
          case 8: { float sg = sigf(ec[gc] + v); float cv = Cf[ci];
                    Cf[ci] = cv + (e1[ci] - cv)*sg; } break;
        }
      }
    }
  }
}

extern "C" void kernel_launch(void* const* d_in, const int* in_sizes, int n_in,
                              void* d_out, int out_size, void* d_ws, size_t ws_size,
                              hipStream_t stream){
  const int*   idx     = (const int*)  d_in[0];
  const float* emb_w   = (const float*)d_in[1];
  const float* ln0_g   = (const float*)d_in[2];
  const float* ln0_b   = (const float*)d_in[3];
  const float* ln1_g   = (const float*)d_in[4];
  const float* ln1_b   = (const float*)d_in[5];
  const float* ln2_g   = (const float*)d_in[6];
  const float* ln2_b   = (const float*)d_in[7];
  const float* lnx_g   = (const float*)d_in[8];
  const float* lnx_b   = (const float*)d_in[9];
  const float* lnout_g = (const float*)d_in[10];
  const float* lnout_b = (const float*)d_in[11];
  const float* x_mix   = (const float*)d_in[12];
  const float* w0      = (const float*)d_in[13];
  const float* w1      = (const float*)d_in[14];
  const float* w2      = (const float*)d_in[15];
  const float* a0      = (const float*)d_in[16];
  const float* a1      = (const float*)d_in[17];
  const float* a2      = (const float*)d_in[18];
  const float* v0      = (const float*)d_in[19];
  const float* v1      = (const float*)d_in[20];
  const float* v2      = (const float*)d_in[21];
  const float* g1      = (const float*)d_in[22];
  const float* g2      = (const float*)d_in[23];
  const float* k_k     = (const float*)d_in[24];
  const float* k_a     = (const float*)d_in[25];
  const float* r_k     = (const float*)d_in[26];
  const float* Wr      = (const float*)d_in[27];
  const float* Wk      = (const float*)d_in[28];
  const float* Wv      = (const float*)d_in[29];
  const float* Wo      = (const float*)d_in[30];
  const float* ffn_xk  = (const float*)d_in[31];
  const float* ffn_k   = (const float*)d_in[32];
  const float* ffn_v   = (const float*)d_in[33];
  const float* tstate  = (const float*)d_in[34];
  const float* head_w  = (const float*)d_in[35];
  float* out = (float*)d_out;

  // -------- workspace carve --------
  char* p = (char*)d_ws;
  auto alloc = [&](size_t bytes)->void*{ void* r = (void*)p; p += (bytes + 255) & ~(size_t)255; return r; };
  float* x      = (float*)alloc((size_t)BTC_*4);
  float* vfirst = (float*)alloc((size_t)BTC_*4);
  float* xin    = (float*)alloc((size_t)BTC_*4);   // scratch: bba
  float* rb     = (float*)alloc((size_t)BTC_*4);
  float* wdec   = (float*)alloc((size_t)BTC_*4);
  float* kb     = (float*)alloc((size_t)BTC_*4);
  float* vb     = (float*)alloc((size_t)BTC_*4);
  float* ab     = (float*)alloc((size_t)BTC_*4);
  float* kkb    = (float*)alloc((size_t)BTC_*4);
  float* yb     = (float*)alloc((size_t)BTC_*4);
  float* gb     = (float*)alloc((size_t)BTC_*4);
  unsigned short* act16 = (unsigned short*)alloc((size_t)6*BTC_*2);
  unsigned short* m_r = act16;
  unsigned short* m_w = act16 + 1*(size_t)BTC_;
  unsigned short* m_k = act16 + 2*(size_t)BTC_;
  unsigned short* m_v = act16 + 3*(size_t)BTC_;
  unsigned short* m_a = act16 + 4*(size_t)BTC_;
  unsigned short* m_g = act16 + 5*(size_t)BTC_;
  unsigned short* yg16  = m_r;   // alias: m6 dead after projections
  unsigned short* kx16  = m_w;
  unsigned short* hid16 = m_k;   // 16MB spans m_k..m_g
  unsigned short* xh16  = m_r;
  unsigned short* w16 = (unsigned short*)alloc((size_t)BT_*128*2);
  unsigned short* a16 = (unsigned short*)alloc((size_t)BT_*128*2);
  unsigned short* v16 = (unsigned short*)alloc((size_t)BT_*128*2);
  unsigned short* g16 = (unsigned short*)alloc((size_t)BT_*128*2);
  unsigned short *WrT[L_], *WkT[L_], *WvT[L_], *WoT[L_];
  unsigned short *w1T[L_], *a1T[L_], *v1T[L_], *g1T[L_];
  unsigned short *w2T[L_], *a2T[L_], *v2T[L_], *g2T[L_];
  unsigned short *fkT[L_], *fvT[L_];
  for (int l = 0; l < L_; l++){
    WrT[l] = (unsigned short*)alloc((size_t)C_*C_*2);
    WkT[l] = (unsigned short*)alloc((size_t)C_*C_*2);
    WvT[l] = (unsigned short*)alloc((size_t)C_*C_*2);
    WoT[l] = (unsigned short*)alloc((size_t)C_*C_*2);
    w1T[l] = (unsigned short*)alloc((size_t)128*C_*2);
    a1T[l] = (unsigned short*)alloc((size_t)128*C_*2);
    v1T[l] = (unsigned short*)alloc((size_t)128*C_*2);
    g1T[l] = (unsigned short*)alloc((size_t)128*C_*2);
    w2T[l] = (unsigned short*)alloc((size_t)C_*64*2);
    a2T[l] = (unsigned short*)alloc((size_t)C_*64*2);
    v2T[l] = (unsigned short*)alloc((size_t)C_*32*2);
    g2T[l] = (unsigned short*)alloc((size_t)C_*128*2);
    fkT[l] = (unsigned short*)alloc((size_t)FF_*C_*2);
    fvT[l] = (unsigned short*)alloc((size_t)C_*FF_*2);
  }
  unsigned short* hwT = (unsigned short*)alloc((size_t)V_*C_*2);

  dim3 blk(256);
  dim3 tcb(32, 8);

  auto MG = [&](const unsigned short* A, int lda, const unsigned short* Bt,
                float* Cf, unsigned short* Cb, int ldc, int M, int Nn, int K, int ep,
                const float* ec = 0, const float* e1 = 0){
    k_mgemm<<<dim3(Nn/128, M/128), 256, 0, stream>>>(
      (const short*)A, lda, (const short*)Bt, Cf, Cb, ldc, K, ep, ec, e1);
  };

  // -------- weight convert/transpose (per call; weights re-read fresh) --------
  for (int l = 0; l < L_; l++){
    k_tc<<<dim3(32,32), tcb, 0, stream>>>(Wr + (size_t)l*C_*C_, WrT[l], C_, C_, C_);
    k_tc<<<dim3(32,32), tcb, 0, stream>>>(Wk + (size_t)l*C_*C_, WkT[l], C_, C_, C_);
    k_tc<<<dim3(32,32), tcb, 0, stream>>>(Wv + (size_t)l*C_*C_, WvT[l], C_, C_, C_);
    k_tc<<<dim3(32,32), tcb, 0, stream>>>(Wo + (size_t)l*C_*C_, WoT[l], C_, C_, C_);
    k_tc<<<dim3(4,32),  tcb, 0, stream>>>(w1 + (size_t)l*C_*DW_, w1T[l], C_, DW_, 128);
    k_tc<<<dim3(4,32),  tcb, 0, stream>>>(a1 + (size_t)l*C_*DA_, a1T[l], C_, DA_, 128);
    k_tc<<<dim3(4,32),  tcb, 0, stream>>>(v1 + (size_t)l*C_*DV_, v1T[l], C_, DV_, 128);
    k_tc<<<dim3(4,32),  tcb, 0, stream>>>(g1 + (size_t)l*C_*DG_, g1T[l], C_, DG_, 128);
    k_tc<<<dim3(32,2),  tcb, 0, stream>>>(w2 + (size_t)l*DW_*C_, w2T[l], DW_, C_, C_);
    k_tc<<<dim3(32,2),  tcb, 0, stream>>>(a2 + (size_t)l*DA_*C_, a2T[l], DA_, C_, C_);
    k_tc<<<dim3(32,1),  tcb, 0, stream>>>(v2 + (size_t)l*DV_*C_, v2T[l], DV_, C_, C_);
    k_tc<<<dim3(32,4),  tcb, 0, stream>>>(g2 + (size_t)l*DG_*C_, g2T[l], DG_, C_, C_);
    k_tc<<<dim3(128,32),tcb, 0, stream>>>(ffn_k + (size_t)l*C_*FF_, fkT[l], C_, FF_, FF_);
    k_tc<<<dim3(32,128),tcb, 0, stream>>>(ffn_v + (size_t)l*FF_*C_, fvT[l], FF_, C_, C_);
  }
  k_tc<<<dim3(1000,32), tcb, 0, stream>>>(head_w, hwT, C_, V_, V_);

  int ewg = (BTC_ + 255)/256;
  k_embed<<<ewg, blk, 0, stream>>>(idx, emb_w, x);

  for (int l = 0; l < L_; l++){
    const float* mixl = x_mix + ((size_t)l*6)*C_;
    if (l == 0)
      k_ln<<<BT_, blk, 0, stream>>>(x, ln0_g, ln0_b, x, (unsigned short*)0);
    // fused LN + token-shift mix -> 6 bf16 matrices
    k_lnmix<<<BT_, blk, 0, stream>>>(x, ln1_g + l*C_, ln1_b + l*C_, mixl, act16);

    // projections (bf16 MFMA)
    MG(m_r, C_, WrT[l], rb, 0, C_, BT_, C_, C_, 0);
    MG(m_w, C_, w1T[l], 0, w16, 128, BT_, 128, C_, 3);   // tanh -> bf16
    MG(m_k, C_, WkT[l], kb, 0, C_, BT_, C_, C_, 0);
    MG(m_v, C_, WvT[l], vb, 0, C_, BT_, C_, C_, 0);
    if (l > 0)
      MG(m_v, C_, v1T[l], 0, v16, 128, BT_, 128, C_, 2);
    MG(m_a, C_, a1T[l], 0, a16, 128, BT_, 128, C_, 2);
    MG(m_g, C_, g1T[l], 0, g16, 128, BT_, 128, C_, 4);   // sigmoid -> bf16

    // second-stage low-rank with fused epilogues
    MG(w16, 128, w2T[l], wdec, 0, C_, BT_, C_, DW_, 6, w0 + l*C_);      // decay
    MG(a16, 128, a2T[l], ab,   0, C_, BT_, C_, DA_, 7, a0 + l*C_);      // a-sigmoid
    if (l == 0){
      hipMemcpyAsync(vfirst, vb, (size_t)BTC_*4, hipMemcpyDeviceToDevice, stream);
    } else {
      MG(v16, 128, v2T[l], vb, 0, C_, BT_, C_, DV_, 8, v0 + l*C_, vfirst); // vmix RMW
    }
    MG(g16, 128, g2T[l], gb, 0, C_, BT_, C_, DG_, 0);

    // kk normalize + k2 + bba  (bba stored in xin scratch)
    k_kk<<<BT_*H_, 64, 0, stream>>>(k_k + l*C_, k_a + l*C_, ab, kb, kkb, xin);

    // sequential scan (fp32), rows split 8-way across blocks
    k_scan<<<B_*H_*(N_/SROWS), 128, 0, stream>>>(rb, kb, vb, wdec, kkb, xin,
                                      tstate + (size_t)l*H_*N_*N_, yb);

    // groupnorm + bonus + *g -> bf16
    k_gnb<<<BT_*H_, 64, 0, stream>>>(lnx_g + l*C_, lnx_b + l*C_, r_k + (size_t)l*H_*N_,
                                     rb, kb, vb, gb, yb, yg16);

    // x += (y*g) @ Wo
    MG(yg16, C_, WoT[l], x, 0, C_, BT_, C_, C_, 1);

    // FFN: fused LN + token-mix -> bf16
    k_lnffn<<<BT_, blk, 0, stream>>>(x, ln2_g + l*C_, ln2_b + l*C_, ffn_xk + l*C_, kx16);
    MG(kx16, C_, fkT[l], 0, hid16, FF_, BT_, FF_, C_, 5);  // relu^2 -> bf16
    MG(hid16, FF_, fvT[l], x, 0, C_, BT_, C_, FF_, 1);
  }

  // head: LN fused with bf16 cast
  k_ln<<<BT_, blk, 0, stream>>>(x, lnout_g, lnout_b, (float*)0, xh16);
  MG(xh16, C_, hwT, out, 0, V_, BT_, V_, C_, 0);
}

// Round 5
// 2138.076 us; speedup vs baseline: 1.2348x; 1.2348x over previous
//
#include <hip/hip_runtime.h>
#include <hip/hip_bf16.h>
#include <math.h>

#define V_  32000
#define C_  1024
#define L_  2
#define H_  16
#define N_  64
#define B_  2
#define T_  1024
#define FF_ 4096
#define DW_ 64
#define DA_ 64
#define DV_ 32
#define DG_ 128
#define BT_  (B_*T_)
#define BTC_ (BT_*C_)

typedef float floatx4 __attribute__((ext_vector_type(4)));
typedef short shortx8 __attribute__((ext_vector_type(8)));
typedef __attribute__((address_space(1))) unsigned int gu32;
typedef __attribute__((address_space(3))) unsigned int su32;

__device__ __forceinline__ float sigf(float x){ return 1.0f/(1.0f+expf(-x)); }
__device__ __forceinline__ unsigned short f2bf(float x){
  __hip_bfloat16 h = __float2bfloat16(x);
  return *(unsigned short*)&h;
}
__device__ __forceinline__ void gload16(const void* g, void* l){
  __builtin_amdgcn_global_load_lds((const gu32*)g, (su32*)l, 16, 0, 0);
}

// 16-lane sum reduction entirely on the VALU via DPP (no DS-pipe shuffles).
__device__ __forceinline__ float dpp_red16(float s){
  s += __int_as_float(__builtin_amdgcn_update_dpp(0, __float_as_int(s), 0xB1, 0xf, 0xf, true));
  s += __int_as_float(__builtin_amdgcn_update_dpp(0, __float_as_int(s), 0x4E, 0xf, 0xf, true));
  s += __int_as_float(__builtin_amdgcn_update_dpp(0, __float_as_int(s), 0x141, 0xf, 0xf, true));
  s += __int_as_float(__builtin_amdgcn_update_dpp(0, __float_as_int(s), 0x140, 0xf, 0xf, true));
  return s;
}

// ---------------- embedding ----------------
__global__ void k_embed(const int* __restrict__ idx, const float* __restrict__ emb,
                        float* __restrict__ x){
  int i = blockIdx.x*256 + threadIdx.x;
  if (i >= BTC_) return;
  int row = i / C_, c = i - row*C_;
  x[i] = emb[(size_t)idx[row]*C_ + c];
}

// ---------------- layernorm (row-wise over C); optional bf16 output ----------------
__global__ void k_ln(const float* __restrict__ x, const float* __restrict__ g,
                     const float* __restrict__ b, float* __restrict__ out,
                     unsigned short* __restrict__ out16){
  int row = blockIdx.x;
  const float* xr = x + (size_t)row*C_;
  float s = 0.f, s2 = 0.f;
  for (int c = threadIdx.x; c < C_; c += 256){ float v = xr[c]; s += v; s2 += v*v; }
  for (int o = 32; o > 0; o >>= 1){ s += __shfl_xor(s,o); s2 += __shfl_xor(s2,o); }
  __shared__ float w1s[4], w2s[4];
  int wid = threadIdx.x >> 6, lane = threadIdx.x & 63;
  if (lane == 0){ w1s[wid] = s; w2s[wid] = s2; }
  __syncthreads();
  if (threadIdx.x == 0){
    float a = 0.f, bb = 0.f;
    for (int i = 0; i < 4; i++){ a += w1s[i]; bb += w2s[i]; }
    w1s[0] = a; w2s[0] = bb;
  }
  __syncthreads();
  float mean = w1s[0] * (1.0f/C_);
  float var  = w2s[0] * (1.0f/C_) - mean*mean;
  float r = rsqrtf(var + 1e-5f);
  if (out16){
    unsigned short* orow = out16 + (size_t)row*C_;
    for (int c = threadIdx.x; c < C_; c += 256)
      orow[c] = f2bf((xr[c]-mean)*r*g[c] + b[c]);
  } else {
    float* orow = out + (size_t)row*C_;
    for (int c = threadIdx.x; c < C_; c += 256)
      orow[c] = (xr[c]-mean)*r*g[c] + b[c];
  }
}

// ---------------- fused LN(row)+LN(prev row)+mix6 -> 6 bf16 matrices ----------------
__global__ void k_lnmix(const float* __restrict__ x, const float* __restrict__ g,
                        const float* __restrict__ b, const float* __restrict__ mixl,
                        unsigned short* __restrict__ m6){
  int row = blockIdx.x;
  int t = row & (T_-1);
  const float* xr = x + (size_t)row*C_;
  const float* xp = xr - C_;
  float s0=0.f,q0=0.f,s1=0.f,q1=0.f;
  for (int c = threadIdx.x; c < C_; c += 256){
    float v = xr[c]; s0 += v; q0 += v*v;
    if (t > 0){ float u = xp[c]; s1 += u; q1 += u*u; }
  }
  for (int o=32;o>0;o>>=1){
    s0+=__shfl_xor(s0,o); q0+=__shfl_xor(q0,o);
    s1+=__shfl_xor(s1,o); q1+=__shfl_xor(q1,o);
  }
  __shared__ float rA[4], rB[4], rC[4], rD[4];
  int wid = threadIdx.x>>6, lane = threadIdx.x&63;
  if (lane==0){ rA[wid]=s0; rB[wid]=q0; rC[wid]=s1; rD[wid]=q1; }
  __syncthreads();
  if (threadIdx.x==0){
    float a=0,bb=0,cc=0,dd=0;
    for(int i=0;i<4;i++){a+=rA[i];bb+=rB[i];cc+=rC[i];dd+=rD[i];}
    rA[0]=a;rB[0]=bb;rC[0]=cc;rD[0]=dd;
  }
  __syncthreads();
  float m0 = rA[0]*(1.f/C_);
  float r0 = rsqrtf(rB[0]*(1.f/C_)-m0*m0 + 1e-5f);
  float m1=0.f, r1=0.f;
  if (t>0){ m1 = rC[0]*(1.f/C_); r1 = rsqrtf(rD[0]*(1.f/C_)-m1*m1 + 1e-5f); }
  size_t base = (size_t)row*C_;
  for (int c = threadIdx.x; c < C_; c += 256){
    float cur = (xr[c]-m0)*r0*g[c]+b[c];
    float pv  = (t>0) ? (xp[c]-m1)*r1*g[c]+b[c] : 0.f;
    float d = pv - cur;
#pragma unroll
    for (int j=0;j<6;j++)
      m6[(size_t)j*BTC_ + base + c] = f2bf(cur + d*mixl[j*C_+c]);
  }
}

// ---------------- fused LN + FFN token-mix -> bf16 ----------------
__global__ void k_lnffn(const float* __restrict__ x, const float* __restrict__ g,
                        const float* __restrict__ b, const float* __restrict__ fxk,
                        unsigned short* __restrict__ kx){
  int row = blockIdx.x;
  int t = row & (T_-1);
  const float* xr = x + (size_t)row*C_;
  const float* xp = xr - C_;
  float s0=0.f,q0=0.f,s1=0.f,q1=0.f;
  for (int c = threadIdx.x; c < C_; c += 256){
    float v = xr[c]; s0 += v; q0 += v*v;
    if (t > 0){ float u = xp[c]; s1 += u; q1 += u*u; }
  }
  for (int o=32;o>0;o>>=1){
    s0+=__shfl_xor(s0,o); q0+=__shfl_xor(q0,o);
    s1+=__shfl_xor(s1,o); q1+=__shfl_xor(q1,o);
  }
  __shared__ float rA[4], rB[4], rC[4], rD[4];
  int wid = threadIdx.x>>6, lane = threadIdx.x&63;
  if (lane==0){ rA[wid]=s0; rB[wid]=q0; rC[wid]=s1; rD[wid]=q1; }
  __syncthreads();
  if (threadIdx.x==0){
    float a=0,bb=0,cc=0,dd=0;
    for(int i=0;i<4;i++){a+=rA[i];bb+=rB[i];cc+=rC[i];dd+=rD[i];}
    rA[0]=a;rB[0]=bb;rC[0]=cc;rD[0]=dd;
  }
  __syncthreads();
  float m0 = rA[0]*(1.f/C_);
  float r0 = rsqrtf(rB[0]*(1.f/C_)-m0*m0 + 1e-5f);
  float m1=0.f, r1=0.f;
  if (t>0){ m1 = rC[0]*(1.f/C_); r1 = rsqrtf(rD[0]*(1.f/C_)-m1*m1 + 1e-5f); }
  size_t base = (size_t)row*C_;
  for (int c = threadIdx.x; c < C_; c += 256){
    float cur = (xr[c]-m0)*r0*g[c]+b[c];
    float pv  = (t>0) ? (xp[c]-m1)*r1*g[c]+b[c] : 0.f;
    kx[base + c] = f2bf(cur + (pv - cur)*fxk[c]);
  }
}

// ---------------- kk normalize + k2 (in-place on k) + bba = -(kk*a) ----------------
__global__ void k_kk(const float* __restrict__ kkw, const float* __restrict__ kaw,
                     const float* __restrict__ a, float* __restrict__ k,
                     float* __restrict__ kk, float* __restrict__ bba){
  int bth = blockIdx.x;
  int lane = threadIdx.x;
  int bt = bth / H_, h = bth - bt*H_;
  int cix = h*N_ + lane;
  size_t gi = (size_t)bt*C_ + cix;
  float kv = k[gi];
  float kkv = kv * kkw[cix];
  float ss = kkv*kkv;
  for (int o = 32; o > 0; o >>= 1) ss += __shfl_xor(ss,o);
  float nrm = fmaxf(sqrtf(ss), 1e-12f);
  float kkn = kkv / nrm;
  kk[gi] = kkn;
  float av = a[gi];
  bba[gi] = -kkn*av;
  k[gi] = kv * (1.f + (av - 1.f)*kaw[cix]);
}

// ---------------- RWKV7 scan: rows split 8-way across blocks ----------
#define SCHUNK 16
#define SROWS  8
__global__ __launch_bounds__(128) void k_scan(
    const float* __restrict__ r, const float* __restrict__ k2,
    const float* __restrict__ v, const float* __restrict__ wd,
    const float* __restrict__ kk, const float* __restrict__ bba,
    const float* __restrict__ S0, float* __restrict__ y){
  int bh = blockIdx.x & 31;
  int rblk = blockIdx.x >> 5;
  int b = bh / H_, h = bh - b*H_;
  int tid = threadIdx.x;
  int wave = tid >> 6, lane = tid & 63;
  int rg = tid >> 4;
  int row = rblk*SROWS + rg;
  int cg = tid & 15;
  int c0 = cg*4;

  // buf[bi][vec][tt][64]; vec: 0=r 1=k2 2=v 3=wd 4=kk 5=bba
  __shared__ __attribute__((aligned(16))) float buf[2][6][SCHUNK][64];

  float S[4];
  {
    const floatx4 s0 = *(const floatx4*)&S0[((size_t)h*N_ + row)*N_ + c0];
#pragma unroll
    for (int ci = 0; ci < 4; ci++) S[ci] = s0[ci];
  }

  size_t hoff = ((size_t)b*T_)*C_ + (size_t)h*N_;

  auto do_stage = [&](int t0, int bi){
#pragma unroll
    for (int q = 0; q < 12; q++){
      int u = wave*12 + q;
      int vec = u >> 2, tt4 = (u & 3)*4;
      int tt = tt4 + (lane >> 4);
      const float* src;
      switch (vec){
        case 0: src = r;   break;
        case 1: src = k2;  break;
        case 2: src = v;   break;
        case 3: src = wd;  break;
        case 4: src = kk;  break;
        default: src = bba; break;
      }
      src += hoff + (size_t)(t0 + tt)*C_ + (size_t)((lane & 15)*4);
      gload16(src, &buf[bi][vec][tt4][0]);
    }
  };

  do_stage(0, 0);
  asm volatile("s_waitcnt vmcnt(0)" ::: "memory");
  __builtin_amdgcn_s_barrier();

  const int NC = T_/SCHUNK;
  size_t off = hoff;
  for (int c = 0; c < NC; c++){
    int bi = c & 1;
    bool more = (c + 1 < NC);
    if (more) do_stage((c+1)*SCHUNK, bi ^ 1);
    asm volatile("" ::: "memory");

    floatx4 rv  = *(const floatx4*)&buf[bi][0][0][c0];
    floatx4 kv  = *(const floatx4*)&buf[bi][1][0][c0];
    float   vi  = buf[bi][2][0][row];
    floatx4 dd  = *(const floatx4*)&buf[bi][3][0][c0];
    floatx4 kkv = *(const floatx4*)&buf[bi][4][0][c0];
    floatx4 bav = *(const floatx4*)&buf[bi][5][0][c0];
#pragma unroll
    for (int tt = 0; tt < SCHUNK; tt++, off += C_){
      floatx4 rv2, kv2, dd2, kkv2, bav2; float vi2;
      if (tt + 1 < SCHUNK){
        rv2  = *(const floatx4*)&buf[bi][0][tt+1][c0];
        kv2  = *(const floatx4*)&buf[bi][1][tt+1][c0];
        vi2  = buf[bi][2][tt+1][row];
        dd2  = *(const floatx4*)&buf[bi][3][tt+1][c0];
        kkv2 = *(const floatx4*)&buf[bi][4][tt+1][c0];
        bav2 = *(const floatx4*)&buf[bi][5][tt+1][c0];
      }
      float s = S[0]*kkv[0];
      s = fmaf(S[1], kkv[1], s);
      s = fmaf(S[2], kkv[2], s);
      s = fmaf(S[3], kkv[3], s);
      float sa = dpp_red16(s);
      float yy = 0.f;
#pragma unroll
      for (int ci = 0; ci < 4; ci++){
        float t0v = fmaf(vi, kv[ci], sa*bav[ci]);
        float sn = fmaf(S[ci], dd[ci], t0v);
        S[ci] = sn;
        yy = fmaf(sn, rv[ci], yy);
      }
      float yv = dpp_red16(yy);
      if (cg == 0) y[off + row] = yv;
      if (tt + 1 < SCHUNK){
        rv = rv2; kv = kv2; vi = vi2; dd = dd2; kkv = kkv2; bav = bav2;
      }
    }
    if (more){
      asm volatile("s_waitcnt vmcnt(16)" ::: "memory");
      __builtin_amdgcn_sched_barrier(0);
      __builtin_amdgcn_s_barrier();
    }
  }
}

// ---------------- groupnorm + bonus + *g -> bf16 ----------------
__global__ void k_gnb(const float* __restrict__ lxg, const float* __restrict__ lxb,
                      const float* __restrict__ rk, const float* __restrict__ r,
                      const float* __restrict__ k2, const float* __restrict__ v,
                      const float* __restrict__ g, const float* __restrict__ y,
                      unsigned short* __restrict__ yg){
  int bth = blockIdx.x;
  int lane = threadIdx.x;
  int bt = bth / H_, h = bth - bt*H_;
  int cix = h*N_ + lane;
  size_t gi = (size_t)bt*C_ + cix;
  float yv = y[gi];
  float s = yv;
  for (int o = 32; o > 0; o >>= 1) s += __shfl_xor(s,o);
  float mean = s * (1.0f/N_);
  float d = yv - mean;
  float s2 = d*d;
  for (int o = 32; o > 0; o >>= 1) s2 += __shfl_xor(s2,o);
  float var = s2 * (1.0f/N_);
  float yn = d * rsqrtf(var + 64e-5f) * lxg[cix] + lxb[cix];
  float dv = r[gi]*k2[gi]*rk[h*N_ + lane];
  for (int o = 32; o > 0; o >>= 1) dv += __shfl_xor(dv,o);
  yg[gi] = f2bf((yn + dv*v[gi]) * g[gi]);
}

// ---------------- weight transpose + fp32->bf16: in [R][Cc] -> out [Cpad][R] ----------------
__global__ void k_tc(const float* __restrict__ in, unsigned short* __restrict__ out,
                     int R, int Cc, int Cpad){
  __shared__ float t[32][33];
  int c0 = blockIdx.x*32, r0 = blockIdx.y*32;
  int tx = threadIdx.x, ty = threadIdx.y;
  for (int i = ty; i < 32; i += 8){
    int r = r0+i, c = c0+tx;
    t[i][tx] = (r < R && c < Cc) ? in[(size_t)r*Cc + c] : 0.f;
  }
  __syncthreads();
  for (int i = ty; i < 32; i += 8){
    int oc = c0+i, orr = r0+tx;
    if (oc < Cpad && orr < R) out[(size_t)oc*R + orr] = f2bf(t[tx][i]);
  }
}

// ---------------- bf16 MFMA GEMM: C = ep(A[M][K](lda) @ Bt[N][K]^T) ----------------
// tile 128x128, BK=32, grid (M/128, N/128) — consecutive blocks share the B-tile.
// LDS XOR-swizzle (chunk ^= (row>>1)&3) applied BOTH on the global_load_lds source
// and the ds_read address -> conflict-free b128 fragment reads (was 8-way).
// EP compile-time: 0=f32, 1=add f32, 2=bf16, 3=tanh16, 4=sig16, 5=relu^2_16,
//                  6=sig(ec+v)*e^-.5 f32, 7=sig(ec+v) f32, 8=vmix RMW f32
template<int EP>
__global__ __launch_bounds__(256) void k_mgemm(
    const short* __restrict__ A, int lda, const short* __restrict__ Bt,
    float* __restrict__ Cf, unsigned short* __restrict__ Cb, int ldc,
    int K, const float* __restrict__ ec, const float* __restrict__ e1){
  __shared__ __attribute__((aligned(16))) short As[128*32];
  __shared__ __attribute__((aligned(16))) short Bs[128*32];
  int m0 = blockIdx.x*128, n0 = blockIdx.y*128;
  int tid = threadIdx.x, wave = tid >> 6, lane = tid & 63;
  int lhi = lane >> 4, llo = lane & 15;
  int wm = wave & 1, wn = wave >> 1;
  int arow = lane >> 2;
  int scol = ((lane & 3) ^ ((arow >> 1) & 3)) * 8;   // pre-swizzled source chunk
  int swz  = (llo >> 1) & 3;                          // read-side swizzle
  floatx4 acc[4][4];
#pragma unroll
  for (int i = 0; i < 4; i++)
#pragma unroll
    for (int j = 0; j < 4; j++) acc[i][j] = (floatx4){0.f,0.f,0.f,0.f};

  for (int k0 = 0; k0 < K; k0 += 32){
#pragma unroll
    for (int q = 0; q < 2; q++){
      int r0 = wave*32 + q*16;
      gload16(A  + (size_t)(m0 + r0 + arow)*lda + k0 + scol, As + r0*32);
      gload16(Bt + (size_t)(n0 + r0 + arow)*K   + k0 + scol, Bs + r0*32);
    }
    __syncthreads();
    shortx8 af[4], bfv[4];
#pragma unroll
    for (int mi = 0; mi < 4; mi++)
      af[mi] = *(const shortx8*)(As + ((wm*64 + mi*16 + llo)*32 + (lhi^swz)*8));
#pragma unroll
    for (int nj = 0; nj < 4; nj++)
      bfv[nj] = *(const shortx8*)(Bs + ((wn*64 + nj*16 + llo)*32 + (lhi^swz)*8));
#pragma unroll
    for (int mi = 0; mi < 4; mi++)
#pragma unroll
      for (int nj = 0; nj < 4; nj++)
        acc[mi][nj] = __builtin_amdgcn_mfma_f32_16x16x32_bf16(af[mi], bfv[nj], acc[mi][nj], 0, 0, 0);
    __syncthreads();
  }
#pragma unroll
  for (int mi = 0; mi < 4; mi++){
#pragma unroll
    for (int nj = 0; nj < 4; nj++){
      int gr0 = m0 + wm*64 + mi*16 + lhi*4;
      int gc  = n0 + wn*64 + nj*16 + llo;
#pragma unroll
      for (int rg = 0; rg < 4; rg++){
        size_t ci = (size_t)(gr0 + rg)*ldc + gc;
        float v = acc[mi][nj][rg];
        if constexpr (EP == 0) Cf[ci] = v;
        else if constexpr (EP == 1) Cf[ci] += v;
        else if constexpr (EP == 2) Cb[ci] = f2bf(v);
        else if constexpr (EP == 3) Cb[ci] = f2bf(tanhf(v));
        else if constexpr (EP == 4) Cb[ci] = f2bf(sigf(v));
        else if constexpr (EP == 5) { float rr = fmaxf(v, 0.f); Cb[ci] = f2bf(rr*rr); }
        else if constexpr (EP == 6) Cf[ci] = sigf(ec[gc] + v) * 0.60653065971263342f;
        else if constexpr (EP == 7) Cf[ci] = sigf(ec[gc] + v);
        else if constexpr (EP == 8) { float sg = sigf(ec[gc] + v); float cv = Cf[ci];
                                      Cf[ci] = cv + (e1[ci] - cv)*sg; }
      }
    }
  }
}

extern "C" void kernel_launch(void* const* d_in, const int* in_sizes, int n_in,
                              void* d_out, int out_size, void* d_ws, size_t ws_size,
                              hipStream_t stream){
  const int*   idx     = (const int*)  d_in[0];
  const float* emb_w   = (const float*)d_in[1];
  const float* ln0_g   = (const float*)d_in[2];
  const float* ln0_b   = (const float*)d_in[3];
  const float* ln1_g   = (const float*)d_in[4];
  const float* ln1_b   = (const float*)d_in[5];
  const float* ln2_g   = (const float*)d_in[6];
  const float* ln2_b   = (const float*)d_in[7];
  const float* lnx_g   = (const float*)d_in[8];
  const float* lnx_b   = (const float*)d_in[9];
  const float* lnout_g = (const float*)d_in[10];
  const float* lnout_b = (const float*)d_in[11];
  const float* x_mix   = (const float*)d_in[12];
  const float* w0      = (const float*)d_in[13];
  const float* w1      = (const float*)d_in[14];
  const float* w2      = (const float*)d_in[15];
  const float* a0      = (const float*)d_in[16];
  const float* a1      = (const float*)d_in[17];
  const float* a2      = (const float*)d_in[18];
  const float* v0      = (const float*)d_in[19];
  const float* v1      = (const float*)d_in[20];
  const float* v2      = (const float*)d_in[21];
  const float* g1      = (const float*)d_in[22];
  const float* g2      = (const float*)d_in[23];
  const float* k_k     = (const float*)d_in[24];
  const float* k_a     = (const float*)d_in[25];
  const float* r_k     = (const float*)d_in[26];
  const float* Wr      = (const float*)d_in[27];
  const float* Wk      = (const float*)d_in[28];
  const float* Wv      = (const float*)d_in[29];
  const float* Wo      = (const float*)d_in[30];
  const float* ffn_xk  = (const float*)d_in[31];
  const float* ffn_k   = (const float*)d_in[32];
  const float* ffn_v   = (const float*)d_in[33];
  const float* tstate  = (const float*)d_in[34];
  const float* head_w  = (const float*)d_in[35];
  float* out = (float*)d_out;

  // -------- workspace carve --------
  char* p = (char*)d_ws;
  auto alloc = [&](size_t bytes)->void*{ void* r = (void*)p; p += (bytes + 255) & ~(size_t)255; return r; };
  float* x      = (float*)alloc((size_t)BTC_*4);
  float* vfirst = (float*)alloc((size_t)BTC_*4);
  float* xin    = (float*)alloc((size_t)BTC_*4);   // scratch: bba
  float* rb     = (float*)alloc((size_t)BTC_*4);
  float* wdec   = (float*)alloc((size_t)BTC_*4);
  float* kb     = (float*)alloc((size_t)BTC_*4);
  float* vb     = (float*)alloc((size_t)BTC_*4);
  float* ab     = (float*)alloc((size_t)BTC_*4);
  float* kkb    = (float*)alloc((size_t)BTC_*4);
  float* yb     = (float*)alloc((size_t)BTC_*4);
  float* gb     = (float*)alloc((size_t)BTC_*4);
  unsigned short* act16 = (unsigned short*)alloc((size_t)6*BTC_*2);
  unsigned short* m_r = act16;
  unsigned short* m_w = act16 + 1*(size_t)BTC_;
  unsigned short* m_k = act16 + 2*(size_t)BTC_;
  unsigned short* m_v = act16 + 3*(size_t)BTC_;
  unsigned short* m_a = act16 + 4*(size_t)BTC_;
  unsigned short* m_g = act16 + 5*(size_t)BTC_;
  unsigned short* yg16  = m_r;   // alias: m6 dead after projections
  unsigned short* kx16  = m_w;
  unsigned short* hid16 = m_k;   // 16MB spans m_k..m_g
  unsigned short* xh16  = m_r;
  unsigned short* w16 = (unsigned short*)alloc((size_t)BT_*128*2);
  unsigned short* a16 = (unsigned short*)alloc((size_t)BT_*128*2);
  unsigned short* v16 = (unsigned short*)alloc((size_t)BT_*128*2);
  unsigned short* g16 = (unsigned short*)alloc((size_t)BT_*128*2);
  unsigned short *WrT[L_], *WkT[L_], *WvT[L_], *WoT[L_];
  unsigned short *w1T[L_], *a1T[L_], *v1T[L_], *g1T[L_];
  unsigned short *w2T[L_], *a2T[L_], *v2T[L_], *g2T[L_];
  unsigned short *fkT[L_], *fvT[L_];
  for (int l = 0; l < L_; l++){
    WrT[l] = (unsigned short*)alloc((size_t)C_*C_*2);
    WkT[l] = (unsigned short*)alloc((size_t)C_*C_*2);
    WvT[l] = (unsigned short*)alloc((size_t)C_*C_*2);
    WoT[l] = (unsigned short*)alloc((size_t)C_*C_*2);
    w1T[l] = (unsigned short*)alloc((size_t)128*C_*2);
    a1T[l] = (unsigned short*)alloc((size_t)128*C_*2);
    v1T[l] = (unsigned short*)alloc((size_t)128*C_*2);
    g1T[l] = (unsigned short*)alloc((size_t)128*C_*2);
    w2T[l] = (unsigned short*)alloc((size_t)C_*64*2);
    a2T[l] = (unsigned short*)alloc((size_t)C_*64*2);
    v2T[l] = (unsigned short*)alloc((size_t)C_*32*2);
    g2T[l] = (unsigned short*)alloc((size_t)C_*128*2);
    fkT[l] = (unsigned short*)alloc((size_t)FF_*C_*2);
    fvT[l] = (unsigned short*)alloc((size_t)C_*FF_*2);
  }
  unsigned short* hwT = (unsigned short*)alloc((size_t)V_*C_*2);

  dim3 blk(256);
  dim3 tcb(32, 8);

  auto MG = [&](const unsigned short* A, int lda, const unsigned short* Bt,
                float* Cf, unsigned short* Cb, int ldc, int M, int Nn, int K, int ep,
                const float* ec = 0, const float* e1 = 0){
    dim3 g(M/128, Nn/128);   // bx = M-tiles (fast): consecutive blocks share B-tile
    const short* As_ = (const short*)A; const short* Bs_ = (const short*)Bt;
    switch (ep){
      case 0: k_mgemm<0><<<g,256,0,stream>>>(As_,lda,Bs_,Cf,Cb,ldc,K,ec,e1); break;
      case 1: k_mgemm<1><<<g,256,0,stream>>>(As_,lda,Bs_,Cf,Cb,ldc,K,ec,e1); break;
      case 2: k_mgemm<2><<<g,256,0,stream>>>(As_,lda,Bs_,Cf,Cb,ldc,K,ec,e1); break;
      case 3: k_mgemm<3><<<g,256,0,stream>>>(As_,lda,Bs_,Cf,Cb,ldc,K,ec,e1); break;
      case 4: k_mgemm<4><<<g,256,0,stream>>>(As_,lda,Bs_,Cf,Cb,ldc,K,ec,e1); break;
      case 5: k_mgemm<5><<<g,256,0,stream>>>(As_,lda,Bs_,Cf,Cb,ldc,K,ec,e1); break;
      case 6: k_mgemm<6><<<g,256,0,stream>>>(As_,lda,Bs_,Cf,Cb,ldc,K,ec,e1); break;
      case 7: k_mgemm<7><<<g,256,0,stream>>>(As_,lda,Bs_,Cf,Cb,ldc,K,ec,e1); break;
      case 8: k_mgemm<8><<<g,256,0,stream>>>(As_,lda,Bs_,Cf,Cb,ldc,K,ec,e1); break;
    }
  };

  // -------- weight convert/transpose (per call; weights re-read fresh) --------
  for (int l = 0; l < L_; l++){
    k_tc<<<dim3(32,32), tcb, 0, stream>>>(Wr + (size_t)l*C_*C_, WrT[l], C_, C_, C_);
    k_tc<<<dim3(32,32), tcb, 0, stream>>>(Wk + (size_t)l*C_*C_, WkT[l], C_, C_, C_);
    k_tc<<<dim3(32,32), tcb, 0, stream>>>(Wv + (size_t)l*C_*C_, WvT[l], C_, C_, C_);
    k_tc<<<dim3(32,32), tcb, 0, stream>>>(Wo + (size_t)l*C_*C_, WoT[l], C_, C_, C_);
    k_tc<<<dim3(4,32),  tcb, 0, stream>>>(w1 + (size_t)l*C_*DW_, w1T[l], C_, DW_, 128);
    k_tc<<<dim3(4,32),  tcb, 0, stream>>>(a1 + (size_t)l*C_*DA_, a1T[l], C_, DA_, 128);
    k_tc<<<dim3(4,32),  tcb, 0, stream>>>(v1 + (size_t)l*C_*DV_, v1T[l], C_, DV_, 128);
    k_tc<<<dim3(4,32),  tcb, 0, stream>>>(g1 + (size_t)l*C_*DG_, g1T[l], C_, DG_, 128);
    k_tc<<<dim3(32,2),  tcb, 0, stream>>>(w2 + (size_t)l*DW_*C_, w2T[l], DW_, C_, C_);
    k_tc<<<dim3(32,2),  tcb, 0, stream>>>(a2 + (size_t)l*DA_*C_, a2T[l], DA_, C_, C_);
    k_tc<<<dim3(32,1),  tcb, 0, stream>>>(v2 + (size_t)l*DV_*C_, v2T[l], DV_, C_, C_);
    k_tc<<<dim3(32,4),  tcb, 0, stream>>>(g2 + (size_t)l*DG_*C_, g2T[l], DG_, C_, C_);
    k_tc<<<dim3(128,32),tcb, 0, stream>>>(ffn_k + (size_t)l*C_*FF_, fkT[l], C_, FF_, FF_);
    k_tc<<<dim3(32,128),tcb, 0, stream>>>(ffn_v + (size_t)l*FF_*C_, fvT[l], FF_, C_, C_);
  }
  k_tc<<<dim3(1000,32), tcb, 0, stream>>>(head_w, hwT, C_, V_, V_);

  int ewg = (BTC_ + 255)/256;
  k_embed<<<ewg, blk, 0, stream>>>(idx, emb_w, x);

  for (int l = 0; l < L_; l++){
    const float* mixl = x_mix + ((size_t)l*6)*C_;
    if (l == 0)
      k_ln<<<BT_, blk, 0, stream>>>(x, ln0_g, ln0_b, x, (unsigned short*)0);
    // fused LN + token-shift mix -> 6 bf16 matrices
    k_lnmix<<<BT_, blk, 0, stream>>>(x, ln1_g + l*C_, ln1_b + l*C_, mixl, act16);

    // projections (bf16 MFMA)
    MG(m_r, C_, WrT[l], rb, 0, C_, BT_, C_, C_, 0);
    MG(m_w, C_, w1T[l], 0, w16, 128, BT_, 128, C_, 3);   // tanh -> bf16
    MG(m_k, C_, WkT[l], kb, 0, C_, BT_, C_, C_, 0);
    MG(m_v, C_, WvT[l], vb, 0, C_, BT_, C_, C_, 0);
    if (l > 0)
      MG(m_v, C_, v1T[l], 0, v16, 128, BT_, 128, C_, 2);
    MG(m_a, C_, a1T[l], 0, a16, 128, BT_, 128, C_, 2);
    MG(m_g, C_, g1T[l], 0, g16, 128, BT_, 128, C_, 4);   // sigmoid -> bf16

    // second-stage low-rank with fused epilogues
    MG(w16, 128, w2T[l], wdec, 0, C_, BT_, C_, DW_, 6, w0 + l*C_);      // decay
    MG(a16, 128, a2T[l], ab,   0, C_, BT_, C_, DA_, 7, a0 + l*C_);      // a-sigmoid
    if (l == 0){
      hipMemcpyAsync(vfirst, vb, (size_t)BTC_*4, hipMemcpyDeviceToDevice, stream);
    } else {
      MG(v16, 128, v2T[l], vb, 0, C_, BT_, C_, DV_, 8, v0 + l*C_, vfirst); // vmix RMW
    }
    MG(g16, 128, g2T[l], gb, 0, C_, BT_, C_, DG_, 0);

    // kk normalize + k2 + bba  (bba stored in xin scratch)
    k_kk<<<BT_*H_, 64, 0, stream>>>(k_k + l*C_, k_a + l*C_, ab, kb, kkb, xin);

    // sequential scan (fp32), rows split 8-way across blocks
    k_scan<<<B_*H_*(N_/SROWS), 128, 0, stream>>>(rb, kb, vb, wdec, kkb, xin,
                                      tstate + (size_t)l*H_*N_*N_, yb);

    // groupnorm + bonus + *g -> bf16
    k_gnb<<<BT_*H_, 64, 0, stream>>>(lnx_g + l*C_, lnx_b + l*C_, r_k + (size_t)l*H_*N_,
                                     rb, kb, vb, gb, yb, yg16);

    // x += (y*g) @ Wo
    MG(yg16, C_, WoT[l], x, 0, C_, BT_, C_, C_, 1);

    // FFN: fused LN + token-mix -> bf16
    k_lnffn<<<BT_, blk, 0, stream>>>(x, ln2_g + l*C_, ln2_b + l*C_, ffn_xk + l*C_, kx16);
    MG(kx16, C_, fkT[l], 0, hid16, FF_, BT_, FF_, C_, 5);  // relu^2 -> bf16
    MG(hid16, FF_, fvT[l], x, 0, C_, BT_, C_, FF_, 1);
  }

  // head: LN fused with bf16 cast
  k_ln<<<BT_, blk, 0, stream>>>(x, lnout_g, lnout_b, (float*)0, xh16);
  MG(xh16, C_, hwT, out, 0, V_, BT_, V_, C_, 0);
}